// Round 6
// baseline (296.480 us; speedup 1.0000x reference)
//
#include <hip/hip_runtime.h>

#define BB 32
#define TT 512
#define DD 768
#define NTHREADS 192            // = DD/4 float4 lanes per row
#define TOK_PER_BLOCK 8         // source tokens per block
#define BLOCKS_PER_BATCH (TT / TOK_PER_BLOCK)   // 64

typedef float f4 __attribute__((ext_vector_type(4)));

// ROUND 6 = SECOND MEASUREMENT ROUND. Round-5 probe: an extra full 210 MB
// store sweep cost +2.4 us (noise) -> output stores are L3-absorbed and
// essentially FREE (out fits in the 256 MB Infinity Cache; probe's dirty
// lines are re-dirtied by the next kernel, zero net HBM traffic).
// Remaining unknown: of the ~122 us that is not the harness's 130-us poison
// fill (840 MB real HBM writes at 81% of peak -- at the write ceiling),
// how much is OUR kernel vs harness restore/launch overhead?
// Probe: run the round-0 kernel TWICE (idempotent -- identical values
// rewritten, masked tail re-zeroed). DeltaDur vs 252.7 = one full kernel
// execution. +20 -> harness floor, declare roofline; +100 -> kernel is
// internally latency-bound and becomes the target.

__global__ __launch_bounds__(NTHREADS) void lr_fused_kernel(
    const float* __restrict__ x, const float* __restrict__ dur,
    float* __restrict__ out, int t_out) {
    __shared__ int scum[TT];
    const int b = blockIdx.y;
    const int tid = threadIdx.x;

    // reps into LDS
    for (int i = tid; i < TT; i += NTHREADS) {
        float d = fmaxf(dur[b * TT + i], 0.0f);
        scum[i] = (int)floorf(d + 0.5f);
    }
    __syncthreads();

    // Hillis-Steele inclusive scan over 512 elements with 192 threads.
    #pragma unroll
    for (int off = 1; off < TT; off <<= 1) {
        const int i0 = tid, i1 = tid + NTHREADS, i2 = tid + 2 * NTHREADS;
        int v0 = (i0 >= off) ? scum[i0 - off] : 0;
        int v1 = (i1 >= off) ? scum[i1 - off] : 0;
        int v2 = (i2 < TT && i2 >= off) ? scum[i2 - off] : 0;
        __syncthreads();
        scum[i0] += v0;
        scum[i1] += v1;
        if (i2 < TT) scum[i2] += v2;
        __syncthreads();
    }

    // Scatter this block's 8 source tokens.
    const int s0 = blockIdx.x * TOK_PER_BLOCK;
    const f4* xb = (const f4*)(x + (size_t)b * TT * DD);
    f4* ob = (f4*)(out + (size_t)b * (size_t)t_out * DD);

    #pragma unroll
    for (int k = 0; k < TOK_PER_BLOCK; ++k) {
        const int t = s0 + k;
        const int start = (t == 0) ? 0 : scum[t - 1];
        const int end = scum[t];
        if (end > start) {                     // block-uniform branch
            const f4 v = xb[(size_t)t * NTHREADS + tid];
            for (int p = start; p < end; ++p)  // 0..8 iters, block-uniform
                __builtin_nontemporal_store(v, &ob[(size_t)p * NTHREADS + tid]);
        }
    }

    // Tail zero: rows [total, t_out) striped across the batch's 64 blocks.
    const int total = scum[TT - 1];
    const f4 z = (f4)(0.0f);
    for (int pos = total + blockIdx.x; pos < t_out; pos += BLOCKS_PER_BATCH)
        __builtin_nontemporal_store(z, &ob[(size_t)pos * NTHREADS + tid]);
}

extern "C" void kernel_launch(void* const* d_in, const int* in_sizes, int n_in,
                              void* d_out, int out_size, void* d_ws, size_t ws_size,
                              hipStream_t stream) {
    const float* x   = (const float*)d_in[0];
    const float* dur = (const float*)d_in[1];
    float* out = (float*)d_out;
    (void)d_ws; (void)ws_size; (void)in_sizes; (void)n_in;

    const int t_out = out_size / (BB * DD);

    dim3 grid(BLOCKS_PER_BATCH, BB);           // 64 x 32 blocks
    // Probe: same kernel twice, back-to-back (idempotent).
    lr_fused_kernel<<<grid, NTHREADS, 0, stream>>>(x, dur, out, t_out);
    lr_fused_kernel<<<grid, NTHREADS, 0, stream>>>(x, dur, out, t_out);
}

// Round 7
// 246.023 us; speedup vs baseline: 1.2051x; 1.2051x over previous
//
#include <hip/hip_runtime.h>

#define BB 32
#define TT 512
#define DD 768
#define NTHREADS 192            // = DD/4 float4 lanes per row
#define TOK_PER_BLOCK 8         // source tokens per block
#define BLOCKS_PER_BATCH (TT / TOK_PER_BLOCK)   // 64

typedef float f4 __attribute__((ext_vector_type(4)));

// Round 7: round-0 kernel + ONE change — hoist all 8 x-row loads to kernel
// entry, before the scan.
// Evidence chain: round-6 double-launch probe measured one kernel execution
// at 43.8 us; round-5 probe measured a standalone 210 MB store sweep at
// +2.4 us (stores are fire-and-forget into L3; output is L3-resident and
// re-dirtied by the next poison fill, never reaching HBM on the critical
// path). x read is only 8 us at BW ceiling. The only remaining structural
// cost is the per-token dependent chain: load x[t] -> vmcnt wait -> store
// burst, 8 sequential HBM round-trips per block under a scan-dependent
// branch. Hoisting the loads (addresses are static per block, always
// in-bounds) lets the ~5000-cycle scan phase hide all load latency; the
// store phase becomes the pure streaming round 5 proved is nearly free.
__global__ __launch_bounds__(NTHREADS) void lr_fused_kernel(
    const float* __restrict__ x, const float* __restrict__ dur,
    float* __restrict__ out, int t_out) {
    __shared__ int scum[TT];
    const int b = blockIdx.y;
    const int tid = threadIdx.x;
    const int s0 = blockIdx.x * TOK_PER_BLOCK;

    const f4* xb = (const f4*)(x + (size_t)b * TT * DD);

    // Issue all 8 row loads NOW; latency hides under the scan below.
    f4 v[TOK_PER_BLOCK];
    #pragma unroll
    for (int k = 0; k < TOK_PER_BLOCK; ++k)
        v[k] = xb[(size_t)(s0 + k) * NTHREADS + tid];

    // reps into LDS
    for (int i = tid; i < TT; i += NTHREADS) {
        float d = fmaxf(dur[b * TT + i], 0.0f);
        scum[i] = (int)floorf(d + 0.5f);
    }
    __syncthreads();

    // Hillis-Steele inclusive scan over 512 elements with 192 threads.
    #pragma unroll
    for (int off = 1; off < TT; off <<= 1) {
        const int i0 = tid, i1 = tid + NTHREADS, i2 = tid + 2 * NTHREADS;
        int v0 = (i0 >= off) ? scum[i0 - off] : 0;
        int v1 = (i1 >= off) ? scum[i1 - off] : 0;
        int v2 = (i2 < TT && i2 >= off) ? scum[i2 - off] : 0;
        __syncthreads();
        scum[i0] += v0;
        scum[i1] += v1;
        if (i2 < TT) scum[i2] += v2;
        __syncthreads();
    }

    // Scatter this block's 8 source tokens from registers.
    f4* ob = (f4*)(out + (size_t)b * (size_t)t_out * DD);

    #pragma unroll
    for (int k = 0; k < TOK_PER_BLOCK; ++k) {
        const int t = s0 + k;
        const int start = (t == 0) ? 0 : scum[t - 1];
        const int end = scum[t];
        for (int p = start; p < end; ++p)      // 0..8 iters, block-uniform
            __builtin_nontemporal_store(v[k], &ob[(size_t)p * NTHREADS + tid]);
    }

    // Tail zero: rows [total, t_out) striped across the batch's 64 blocks.
    const int total = scum[TT - 1];
    const f4 z = (f4)(0.0f);
    for (int pos = total + blockIdx.x; pos < t_out; pos += BLOCKS_PER_BATCH)
        __builtin_nontemporal_store(z, &ob[(size_t)pos * NTHREADS + tid]);
}

extern "C" void kernel_launch(void* const* d_in, const int* in_sizes, int n_in,
                              void* d_out, int out_size, void* d_ws, size_t ws_size,
                              hipStream_t stream) {
    const float* x   = (const float*)d_in[0];
    const float* dur = (const float*)d_in[1];
    float* out = (float*)d_out;
    (void)d_ws; (void)ws_size; (void)in_sizes; (void)n_in;

    const int t_out = out_size / (BB * DD);

    dim3 grid(BLOCKS_PER_BATCH, BB);           // 64 x 32 blocks
    lr_fused_kernel<<<grid, NTHREADS, 0, stream>>>(x, dur, out, t_out);
}